// Round 5
// baseline (146.492 us; speedup 1.0000x reference)
//
#include <hip/hip_runtime.h>
#include <math.h>

#define VOCAB  50000
#define D_EMB  300
#define NBINS  11
#define BATCH  64
#define LQ     32
#define LD     1024
#define DTILE  64
#define NDT    (LD / DTILE)   // 16
#define NSTEP  10             // K padded to 320 = 10 * 32 (MFMA K=32 steps)
#define FRAG_SHORTS (NSTEP * 512)   // 5120 shorts per 16-row fragment region

typedef __attribute__((ext_vector_type(8))) short short8;   // 8 bf16 (4 VGPRs)
typedef __attribute__((ext_vector_type(4))) float floatx4;  // MFMA C/D

__constant__ float c_mu[NBINS]  = {1.0f, 0.9f, 0.7f, 0.5f, 0.3f, 0.1f,
                                   -0.1f, -0.3f, -0.5f, -0.7f, -0.9f};
// 1 / (2*sigma^2): sigma=1e-3 -> 5e5 ; sigma=0.1 -> 50
__constant__ float c_is2[NBINS] = {500000.0f, 50.f, 50.f, 50.f, 50.f, 50.f,
                                   50.f, 50.f, 50.f, 50.f, 50.f};

static __device__ __forceinline__ unsigned short f32_bf16(float f) {
  unsigned u = __float_as_uint(f);
  u += 0x7FFFu + ((u >> 16) & 1u);          // RNE
  return (unsigned short)(u >> 16);
}
static __device__ __forceinline__ float bf16_f32(unsigned short h) {
  return __uint_as_float(((unsigned)h) << 16);
}

// Convert one 16-row region into MFMA-fragment-linear layout in GLOBAL memory.
// Lane l holds row (l&15), k-chunk 8*(l>>4) of each 32-wide k-step; writes are
// 16 B/lane contiguous (1 KB/instruction). Sum-of-squares is accumulated over
// the bf16-ROUNDED values in a FIXED per-row order + fixed shuffle tree, so
// any two instances of the same token get bitwise-identical fragments AND
// norms -> exact-match sim == 1 +- 1e-7 -> sigma=1e-3 bin stays exact.
static __device__ __forceinline__ float stage_rows(
    const float* __restrict__ emb_row,   // word_emb + tok*D_EMB (this lane's row)
    short* __restrict__ region, int khi, int lane)
{
  const float4* emb4 = (const float4*)emb_row;
  float p = 0.f;
#pragma unroll
  for (int s = 0; s < NSTEP; ++s) {
    const int k0 = 32 * s + 8 * khi;
    float4 fa = make_float4(0.f, 0.f, 0.f, 0.f);
    float4 fb = make_float4(0.f, 0.f, 0.f, 0.f);
    if (k0 < D_EMB)     fa = emb4[k0 >> 2];        // k0 mult of 8 -> full float4 ok
    if (k0 + 4 < D_EMB) fb = emb4[(k0 >> 2) + 1];  // zero-pad K 300..319
    unsigned short h[8];
    h[0] = f32_bf16(fa.x); h[1] = f32_bf16(fa.y);
    h[2] = f32_bf16(fa.z); h[3] = f32_bf16(fa.w);
    h[4] = f32_bf16(fb.x); h[5] = f32_bf16(fb.y);
    h[6] = f32_bf16(fb.z); h[7] = f32_bf16(fb.w);
    short8 v;
#pragma unroll
    for (int j = 0; j < 8; ++j) {
      const float x = bf16_f32(h[j]);   // norm from ROUNDED values
      p += x * x;
      v[j] = (short)h[j];
    }
    *(short8*)(region + s * 512 + lane * 8) = v;
  }
  return p;
}

// Expand: one wave per 16-row fragment region of the ACTUAL token instances
// (per batch: 2 q-regions + 64 d-regions = 66; padded to 68 -> grid 17x64).
// Gathers f32 rows (L3-resident 60 MB), writes bf16 fragments per-(b,tile)
// so knrm_main reads pure coalesced streams. Also emits per-instance invnorm.
__global__ __launch_bounds__(256) void knrm_expand(
    const int* __restrict__ inputs_q, const int* __restrict__ inputs_d,
    const float* __restrict__ word_emb, short* __restrict__ afrag,
    short* __restrict__ dfrag, float* __restrict__ invq,
    float* __restrict__ invd)
{
  const int b    = blockIdx.y;
  const int i    = blockIdx.x * 4 + (threadIdx.x >> 6);  // region id 0..67
  const int lane = threadIdx.x & 63;
  const int khi  = lane >> 4, rl = lane & 15;
  if (i >= 66) return;

  int tok; short* dst;
  if (i < 2) {                         // q region (q-tile i)
    tok = inputs_q[b * LQ + i * 16 + rl];
    dst = afrag + (size_t)(b * 2 + i) * FRAG_SHORTS;
  } else {                             // d region g = i-2 (d rows 16g..16g+15)
    const int g = i - 2;
    tok = inputs_d[b * LD + g * 16 + rl];
    dst = dfrag + (size_t)(b * 64 + g) * FRAG_SHORTS;
  }
  float p = stage_rows(word_emb + (size_t)tok * D_EMB, dst, khi, lane);
  p += __shfl_xor(p, 16); p += __shfl_xor(p, 32);
  if (lane < 16) {
    const float inv = 1.f / fmaxf(sqrtf(p), 1e-12f);
    if (i < 2) invq[b * LQ + i * 16 + lane] = inv;
    else       invd[b * LD + (i - 2) * 16 + lane] = inv;
  }
}

// Main: one block = (batch b, 64-d tile). ZERO gathers: all operand loads are
// contiguous 1 KB/instruction streams from the fragment buffers (L3/L2-hot).
// Wave w = (qt = w>>1, dp = w&1) computes C tiles qt x {2dp, 2dp+1}.
__global__ __launch_bounds__(256) void knrm_main(
    const float* __restrict__ mask_d, const short* __restrict__ afrag,
    const short* __restrict__ dfrag, const float* __restrict__ invq,
    const float* __restrict__ invd, float* __restrict__ partial)
{
  const int b    = blockIdx.y;
  const int dt   = blockIdx.x;
  const int tid  = threadIdx.x;
  const int wid  = tid >> 6;
  const int lane = tid & 63;
  const int khi  = lane >> 4;   // 0..3
  const int rl   = lane & 15;   // 0..15
  const int qt   = wid >> 1;
  const int dp   = wid & 1;

  __shared__ float red[4][16][NBINS];   // 2.8 KB total LDS

  const short8* arow = (const short8*)(afrag + (size_t)(b * 2 + qt) * FRAG_SHORTS);
  const short8* b0r  = (const short8*)(dfrag + (size_t)(b * 64 + dt * 4 + 2 * dp) * FRAG_SHORTS);
  const short8* b1r  = b0r + FRAG_SHORTS / 8;

  floatx4 acc0 = {0.f, 0.f, 0.f, 0.f};
  floatx4 acc1 = {0.f, 0.f, 0.f, 0.f};
#pragma unroll
  for (int s = 0; s < NSTEP; ++s) {
    const short8 a  = arow[s * 64 + lane];
    const short8 b0 = b0r [s * 64 + lane];
    const short8 b1 = b1r [s * 64 + lane];
    acc0 = __builtin_amdgcn_mfma_f32_16x16x32_bf16(a, b0, acc0, 0, 0, 0);
    acc1 = __builtin_amdgcn_mfma_f32_16x16x32_bf16(a, b1, acc1, 0, 0, 0);
  }

  // ---- epilogue: normalize, RBF bins, pool over this wave's 32 d-cols
  // C/D: col = rl, row = 4*khi + r. iq for row m via wave shuffle from lane m.
  const int dbase = b * LD + dt * DTILE;
  const float iq_own = invq[b * LQ + 16 * qt + rl];
  float iq[4];
#pragma unroll
  for (int r = 0; r < 4; ++r) iq[r] = __shfl(iq_own, 4 * khi + r);
  const float id0 = invd[dbase + 32 * dp + rl];
  const float id1 = invd[dbase + 32 * dp + 16 + rl];
  const float md0 = mask_d[dbase + 32 * dp + rl];
  const float md1 = mask_d[dbase + 32 * dp + 16 + rl];

  float ps[4][NBINS];
#pragma unroll
  for (int r = 0; r < 4; ++r) {
    const float s0 = acc0[r] * iq[r] * id0;
    const float s1 = acc1[r] * iq[r] * id1;
#pragma unroll
    for (int k = 0; k < NBINS; ++k) {
      const float d0 = s0 - c_mu[k];
      const float d1 = s1 - c_mu[k];
      ps[r][k] = md0 * __expf(-d0 * d0 * c_is2[k])
               + md1 * __expf(-d1 * d1 * c_is2[k]);
    }
  }

#pragma unroll
  for (int off = 1; off < 16; off <<= 1)
#pragma unroll
    for (int r = 0; r < 4; ++r)
#pragma unroll
      for (int k = 0; k < NBINS; ++k)
        ps[r][k] += __shfl_xor(ps[r][k], off);

  if (rl == 0)
#pragma unroll
    for (int r = 0; r < 4; ++r)
#pragma unroll
      for (int k = 0; k < NBINS; ++k)
        red[wid][4 * khi + r][k] = ps[r][k];
  __syncthreads();

  // partial layout: [b][q][k][dt] so finalize reads 16 contiguous floats
  for (int v = tid; v < LQ * NBINS; v += 256) {
    const int q = v / NBINS, k = v % NBINS;
    const float sv = (q < 16) ? (red[0][q][k] + red[1][q][k])
                              : (red[2][q - 16][k] + red[3][q - 16][k]);
    partial[((size_t)(b * LQ + q) * NBINS + k) * NDT + dt] = sv;
  }
}

// Finalize: reduce d-tiles, log, IDF attention weight, sum over q, dense+tanh.
__global__ __launch_bounds__(128) void knrm_finalize(
    const float* __restrict__ partial, const int* __restrict__ inputs_q,
    const float* __restrict__ mask_q, const float* __restrict__ attn_table,
    const float* __restrict__ idf_w, const float* __restrict__ idf_b,
    const float* __restrict__ dense_w, const float* __restrict__ dense_b,
    float* __restrict__ out)
{
  const int b   = blockIdx.x;
  const int tid = threadIdx.x;
  __shared__ float pool[LQ][NBINS];
  __shared__ float wq_s[LQ];
  __shared__ float lps[NBINS];

  for (int v = tid; v < LQ * NBINS; v += 128) {
    const int q = v / NBINS, k = v % NBINS;
    const float* p = partial + ((size_t)(b * LQ + q) * NBINS + k) * NDT;
    float s = 0.f;
#pragma unroll
    for (int t = 0; t < NDT; ++t) s += p[t];
    pool[q][k] = logf(fmaxf(s, 1e-10f));
  }
  if (tid < LQ) {
    const int tok = inputs_q[b * LQ + tid];
    wq_s[tid] = mask_q[b * LQ + tid] * (attn_table[tok] * idf_w[0] + idf_b[0]);
  }
  __syncthreads();
  if (tid < NBINS) {
    float s = 0.f;
    for (int q = 0; q < LQ; ++q) s += pool[q][tid] * wq_s[q];
    lps[tid] = 0.01f * s;
  }
  __syncthreads();
  if (tid == 0) {
    float z = dense_b[0];
    for (int k = 0; k < NBINS; ++k) z += lps[k] * dense_w[k];
    out[b] = tanhf(z);
  }
}

extern "C" void kernel_launch(void* const* d_in, const int* in_sizes, int n_in,
                              void* d_out, int out_size, void* d_ws, size_t ws_size,
                              hipStream_t stream) {
  const int*   inputs_q  = (const int*)d_in[0];
  const int*   inputs_d  = (const int*)d_in[1];
  const float* mask_q    = (const float*)d_in[2];
  const float* mask_d    = (const float*)d_in[3];
  const float* word_emb  = (const float*)d_in[4];
  const float* attn_tab  = (const float*)d_in[5];
  const float* idf_w     = (const float*)d_in[6];
  const float* idf_b     = (const float*)d_in[7];
  const float* dense_w   = (const float*)d_in[8];
  const float* dense_b   = (const float*)d_in[9];
  float* out = (float*)d_out;

  // ws layout (256 MiB available):
  //   partial @ 0     : 64*32*11*16 f32        = 1.44 MB
  //   afrag   @ 2 MB  : 64*2  regions * 10 KB  = 1.31 MB
  //   dfrag   @ 4 MB  : 64*64 regions * 10 KB  = 41.9 MB
  //   invq    @ 48 MB : 2048 f32
  //   invd    @ 49 MB : 65536 f32
  char*  ws      = (char*)d_ws;
  float* partial = (float*)ws;
  short* afrag   = (short*)(ws + (2u  << 20));
  short* dfrag   = (short*)(ws + (4u  << 20));
  float* invq    = (float*)(ws + (48u << 20));
  float* invd    = (float*)(ws + (49u << 20));

  dim3 egrid(17, BATCH);   // 68 region slots/batch (66 used), 4 waves/block
  knrm_expand<<<egrid, 256, 0, stream>>>(inputs_q, inputs_d, word_emb,
                                         afrag, dfrag, invq, invd);
  dim3 grid(NDT, BATCH);
  knrm_main<<<grid, 256, 0, stream>>>(mask_d, afrag, dfrag, invq, invd, partial);
  knrm_finalize<<<BATCH, 128, 0, stream>>>(partial, inputs_q, mask_q, attn_tab,
                                           idf_w, idf_b, dense_w, dense_b, out);
}

// Round 6
// 141.884 us; speedup vs baseline: 1.0325x; 1.0325x over previous
//
#include <hip/hip_runtime.h>
#include <math.h>

#define VOCAB   50000
#define D_EMB   300
#define NBINS   11
#define BATCH   64
#define LQ      32
#define LD      1024
#define NCHUNK  8                    // d-chunks per batch, 128 d-rows each
#define NSTEP   10                   // K padded to 320 = 10 * 32
#define FRAG_SHORTS (NSTEP * 512)    // shorts per 16-row fragment region

typedef __attribute__((ext_vector_type(8))) short short8;   // 8 bf16 (4 VGPRs)
typedef __attribute__((ext_vector_type(4))) float floatx4;  // MFMA C/D

__constant__ float c_mu[NBINS]  = {1.0f, 0.9f, 0.7f, 0.5f, 0.3f, 0.1f,
                                   -0.1f, -0.3f, -0.5f, -0.7f, -0.9f};
// 1 / (2*sigma^2): sigma=1e-3 -> 5e5 ; sigma=0.1 -> 50
__constant__ float c_is2[NBINS] = {500000.0f, 50.f, 50.f, 50.f, 50.f, 50.f,
                                   50.f, 50.f, 50.f, 50.f, 50.f};

static __device__ __forceinline__ unsigned short f32_bf16(float f) {
  unsigned u = __float_as_uint(f);
  u += 0x7FFFu + ((u >> 16) & 1u);          // RNE
  return (unsigned short)(u >> 16);
}
static __device__ __forceinline__ float bf16_f32(unsigned short h) {
  return __uint_as_float(((unsigned)h) << 16);
}

// Gather one 16-row region (lane l: row l&15, k-chunk 8*(l>>4) of each 32-k
// step) from f32 word_emb, convert to bf16 IN REGISTERS (frag = MFMA operand
// layout directly), and return this lane's sum-of-squares partial over the
// ROUNDED values. The arithmetic order here + the caller's fixed shfl tree is
// the canonical norm: any two instances of the same token (q or d) produce
// bitwise-identical fragments AND norms -> exact-match sim*iq*id = 1 +- 1e-7
// -> sigma=1e-3 bin-0 stays exact. (No -ffast-math: compiler cannot reorder.)
static __device__ __forceinline__ float gather_convert(
    const float* __restrict__ emb_row, short8* __restrict__ frag,
    int khi)
{
  const float4* emb4 = (const float4*)emb_row;
  float p = 0.f;
#pragma unroll
  for (int s = 0; s < NSTEP; ++s) {
    const int k0 = 32 * s + 8 * khi;
    float4 fa = make_float4(0.f, 0.f, 0.f, 0.f);
    float4 fb = make_float4(0.f, 0.f, 0.f, 0.f);
    if (k0 < D_EMB)     fa = emb4[k0 >> 2];        // k0 mult of 8 -> full float4 ok
    if (k0 + 4 < D_EMB) fb = emb4[(k0 >> 2) + 1];  // zero-pad K 300..319
    unsigned short h[8];
    h[0] = f32_bf16(fa.x); h[1] = f32_bf16(fa.y);
    h[2] = f32_bf16(fa.z); h[3] = f32_bf16(fa.w);
    h[4] = f32_bf16(fb.x); h[5] = f32_bf16(fb.y);
    h[6] = f32_bf16(fb.z); h[7] = f32_bf16(fb.w);
    short8 v;
#pragma unroll
    for (int j = 0; j < 8; ++j) {
      const float x = bf16_f32(h[j]);
      p += x * x;
      v[j] = (short)h[j];
    }
    frag[s] = v;
  }
  return p;
}

// Fused kernel: block = (batch b, 128-d chunk). Every embedding row is read
// from HBM exactly once per consuming block; B fragments live in registers
// (gather layout == MFMA operand layout), A (32 q rows) staged once via LDS.
// Wave w owns d-rows 32w..32w+31 (two 16-row subtiles).
__global__ __launch_bounds__(256, 2) void knrm_fused(
    const int* __restrict__ inputs_q, const int* __restrict__ inputs_d,
    const float* __restrict__ mask_d, const float* __restrict__ word_emb,
    float* __restrict__ partial)
{
  const int b    = blockIdx.y;
  const int j    = blockIdx.x;          // d-chunk 0..7
  const int tid  = threadIdx.x;
  const int wid  = tid >> 6;
  const int lane = tid & 63;
  const int khi  = lane >> 4;           // 0..3
  const int rl   = lane & 15;           // 0..15

  __shared__ __align__(16) short Alds[2 * FRAG_SHORTS];   // 20 KB (2 q-tiles)
  __shared__ float invq_lds[LQ];
  __shared__ float red[4][2][16][NBINS];                  // 5.5 KB

  const int dbase = b * LD + j * 128 + 32 * wid;          // this wave's d rows

  // ---- gather + convert B subtiles into registers (all waves)
  const int td0 = inputs_d[dbase + rl];
  const int td1 = inputs_d[dbase + 16 + rl];
  short8 bf0[NSTEP], bf1[NSTEP];
  float pb0 = gather_convert(word_emb + (size_t)td0 * D_EMB, bf0, khi);
  float pb1 = gather_convert(word_emb + (size_t)td1 * D_EMB, bf1, khi);
  pb0 += __shfl_xor(pb0, 16); pb0 += __shfl_xor(pb0, 32);
  pb1 += __shfl_xor(pb1, 16); pb1 += __shfl_xor(pb1, 32);
  const float id0 = 1.f / fmaxf(sqrtf(pb0), 1e-12f);   // own col (subtile 0)
  const float id1 = 1.f / fmaxf(sqrtf(pb1), 1e-12f);   // own col (subtile 1)

  // ---- waves 0,1: stage q-tile wid into LDS (same canonical conversion)
  if (wid < 2) {
    const int tq = inputs_q[b * LQ + 16 * wid + rl];
    short8 af[NSTEP];
    float pa = gather_convert(word_emb + (size_t)tq * D_EMB, af, khi);
    short8* dst = (short8*)(Alds + wid * FRAG_SHORTS);
#pragma unroll
    for (int s = 0; s < NSTEP; ++s) dst[s * 64 + lane] = af[s];
    pa += __shfl_xor(pa, 16); pa += __shfl_xor(pa, 32);
    if (lane < 16) invq_lds[16 * wid + lane] = 1.f / fmaxf(sqrtf(pa), 1e-12f);
  }
  __syncthreads();

  // ---- MFMA: acc[qt][sub], A from LDS (b128 reads), B from registers
  floatx4 acc[2][2] = {{{0.f,0.f,0.f,0.f},{0.f,0.f,0.f,0.f}},
                       {{0.f,0.f,0.f,0.f},{0.f,0.f,0.f,0.f}}};
#pragma unroll
  for (int s = 0; s < NSTEP; ++s) {
    const short8 a0 = *(const short8*)(Alds + s * 512 + lane * 8);
    const short8 a1 = *(const short8*)(Alds + FRAG_SHORTS + s * 512 + lane * 8);
    acc[0][0] = __builtin_amdgcn_mfma_f32_16x16x32_bf16(a0, bf0[s], acc[0][0], 0, 0, 0);
    acc[0][1] = __builtin_amdgcn_mfma_f32_16x16x32_bf16(a0, bf1[s], acc[0][1], 0, 0, 0);
    acc[1][0] = __builtin_amdgcn_mfma_f32_16x16x32_bf16(a1, bf0[s], acc[1][0], 0, 0, 0);
    acc[1][1] = __builtin_amdgcn_mfma_f32_16x16x32_bf16(a1, bf1[s], acc[1][1], 0, 0, 0);
  }

  // ---- epilogue: normalize, RBF, pool over this wave's 32 d-cols
  // C/D layout: col = rl (d row within subtile), row = 4*khi + r (q within qt)
  const float md0 = mask_d[dbase + rl];
  const float md1 = mask_d[dbase + 16 + rl];
#pragma unroll
  for (int qt = 0; qt < 2; ++qt) {
    float ps[4][NBINS];
#pragma unroll
    for (int r = 0; r < 4; ++r) {
      const float iq = invq_lds[16 * qt + 4 * khi + r];
      const float s0 = acc[qt][0][r] * iq * id0;
      const float s1 = acc[qt][1][r] * iq * id1;
#pragma unroll
      for (int k = 0; k < NBINS; ++k) {
        const float d0 = s0 - c_mu[k];
        const float d1 = s1 - c_mu[k];
        ps[r][k] = md0 * __expf(-d0 * d0 * c_is2[k])
                 + md1 * __expf(-d1 * d1 * c_is2[k]);
      }
    }
#pragma unroll
    for (int off = 1; off < 16; off <<= 1)
#pragma unroll
      for (int r = 0; r < 4; ++r)
#pragma unroll
        for (int k = 0; k < NBINS; ++k)
          ps[r][k] += __shfl_xor(ps[r][k], off);
    if (rl == 0)
#pragma unroll
      for (int r = 0; r < 4; ++r)
#pragma unroll
        for (int k = 0; k < NBINS; ++k)
          red[wid][qt][4 * khi + r][k] = ps[r][k];
  }
  __syncthreads();

  // combine 4 waves; partial layout [b][q][k][chunk] (finalize reads 8 floats)
  for (int v = tid; v < LQ * NBINS; v += 256) {
    const int q = v / NBINS, k = v % NBINS;
    const int qt = q >> 4, qr = q & 15;
    const float sv = red[0][qt][qr][k] + red[1][qt][qr][k]
                   + red[2][qt][qr][k] + red[3][qt][qr][k];
    partial[((size_t)(b * LQ + q) * NBINS + k) * NCHUNK + j] = sv;
  }
}

// Finalize: reduce chunks, log, IDF attention weight, sum over q, dense+tanh.
__global__ __launch_bounds__(128) void knrm_finalize(
    const float* __restrict__ partial, const int* __restrict__ inputs_q,
    const float* __restrict__ mask_q, const float* __restrict__ attn_table,
    const float* __restrict__ idf_w, const float* __restrict__ idf_b,
    const float* __restrict__ dense_w, const float* __restrict__ dense_b,
    float* __restrict__ out)
{
  const int b   = blockIdx.x;
  const int tid = threadIdx.x;
  __shared__ float pool[LQ][NBINS];
  __shared__ float wq_s[LQ];
  __shared__ float lps[NBINS];

  for (int v = tid; v < LQ * NBINS; v += 128) {
    const int q = v / NBINS, k = v % NBINS;
    const float* p = partial + ((size_t)(b * LQ + q) * NBINS + k) * NCHUNK;
    float s = 0.f;
#pragma unroll
    for (int t = 0; t < NCHUNK; ++t) s += p[t];
    pool[q][k] = logf(fmaxf(s, 1e-10f));
  }
  if (tid < LQ) {
    const int tok = inputs_q[b * LQ + tid];
    wq_s[tid] = mask_q[b * LQ + tid] * (attn_table[tok] * idf_w[0] + idf_b[0]);
  }
  __syncthreads();
  if (tid < NBINS) {
    float s = 0.f;
    for (int q = 0; q < LQ; ++q) s += pool[q][tid] * wq_s[q];
    lps[tid] = 0.01f * s;
  }
  __syncthreads();
  if (tid == 0) {
    float z = dense_b[0];
    for (int k = 0; k < NBINS; ++k) z += lps[k] * dense_w[k];
    out[b] = tanhf(z);
  }
}

extern "C" void kernel_launch(void* const* d_in, const int* in_sizes, int n_in,
                              void* d_out, int out_size, void* d_ws, size_t ws_size,
                              hipStream_t stream) {
  const int*   inputs_q  = (const int*)d_in[0];
  const int*   inputs_d  = (const int*)d_in[1];
  const float* mask_q    = (const float*)d_in[2];
  const float* mask_d    = (const float*)d_in[3];
  const float* word_emb  = (const float*)d_in[4];
  const float* attn_tab  = (const float*)d_in[5];
  const float* idf_w     = (const float*)d_in[6];
  const float* idf_b     = (const float*)d_in[7];
  const float* dense_w   = (const float*)d_in[8];
  const float* dense_b   = (const float*)d_in[9];
  float* out     = (float*)d_out;
  float* partial = (float*)d_ws;   // 64*32*11*8 f32 = 0.72 MB

  dim3 grid(NCHUNK, BATCH);        // 512 blocks = 2 per CU
  knrm_fused<<<grid, 256, 0, stream>>>(inputs_q, inputs_d, mask_d, word_emb, partial);
  knrm_finalize<<<BATCH, 128, 0, stream>>>(partial, inputs_q, mask_q, attn_tab,
                                           idf_w, idf_b, dense_w, dense_b, out);
}

// Round 7
// 139.237 us; speedup vs baseline: 1.0521x; 1.0190x over previous
//
#include <hip/hip_runtime.h>
#include <math.h>

#define VOCAB   50000
#define D_EMB   300
#define NBINS   11
#define BATCH   64
#define LQ      32
#define LD      1024
#define NCHUNK  16                   // d-chunks per batch, 64 d-rows each
#define NSTEP   10                   // K padded to 320 = 10 * 32
#define FRAG_SHORTS (NSTEP * 512)    // shorts per 16-row fragment region

typedef __attribute__((ext_vector_type(8))) short short8;   // 8 bf16 (4 VGPRs)
typedef __attribute__((ext_vector_type(4))) float floatx4;  // MFMA C/D

__constant__ float c_mu[NBINS]  = {1.0f, 0.9f, 0.7f, 0.5f, 0.3f, 0.1f,
                                   -0.1f, -0.3f, -0.5f, -0.7f, -0.9f};
// 1 / (2*sigma^2): sigma=1e-3 -> 5e5 ; sigma=0.1 -> 50
__constant__ float c_is2[NBINS] = {500000.0f, 50.f, 50.f, 50.f, 50.f, 50.f,
                                   50.f, 50.f, 50.f, 50.f, 50.f};

static __device__ __forceinline__ unsigned short f32_bf16(float f) {
  unsigned u = __float_as_uint(f);
  u += 0x7FFFu + ((u >> 16) & 1u);          // RNE
  return (unsigned short)(u >> 16);
}
static __device__ __forceinline__ float bf16_f32(unsigned short h) {
  return __uint_as_float(((unsigned)h) << 16);
}

// Gather one 16-row region (lane l: row l&15, k-chunk 8*(l>>4) of each 32-k
// step) from f32 word_emb and convert to bf16. Two variants: to registers
// (frag == MFMA B-operand layout directly) and to LDS (A staging, b128
// writes at base+lane*16, conflict-free). Both use the SAME arithmetic order
// for the sum-of-squares partial; with the caller's fixed shfl tree this
// makes norms bitwise-canonical per token -> exact-match sim*iq*id = 1+-1e-7
// -> sigma=1e-3 bin-0 stays exact. (No -ffast-math: no reordering.)
static __device__ __forceinline__ float gather_convert(
    const float* __restrict__ emb_row, short8* __restrict__ frag, int khi)
{
  const float4* emb4 = (const float4*)emb_row;
  float p = 0.f;
#pragma unroll
  for (int s = 0; s < NSTEP; ++s) {
    const int k0 = 32 * s + 8 * khi;
    float4 fa = make_float4(0.f, 0.f, 0.f, 0.f);
    float4 fb = make_float4(0.f, 0.f, 0.f, 0.f);
    if (k0 < D_EMB)     fa = emb4[k0 >> 2];        // k0 mult of 8 -> full float4 ok
    if (k0 + 4 < D_EMB) fb = emb4[(k0 >> 2) + 1];  // zero-pad K 300..319
    unsigned short h[8];
    h[0] = f32_bf16(fa.x); h[1] = f32_bf16(fa.y);
    h[2] = f32_bf16(fa.z); h[3] = f32_bf16(fa.w);
    h[4] = f32_bf16(fb.x); h[5] = f32_bf16(fb.y);
    h[6] = f32_bf16(fb.z); h[7] = f32_bf16(fb.w);
    short8 v;
#pragma unroll
    for (int j = 0; j < 8; ++j) {
      const float x = bf16_f32(h[j]);
      p += x * x;
      v[j] = (short)h[j];
    }
    frag[s] = v;
  }
  return p;
}

static __device__ __forceinline__ float gather_convert_lds(
    const float* __restrict__ emb_row, short* __restrict__ region,
    int khi, int lane)
{
  const float4* emb4 = (const float4*)emb_row;
  float p = 0.f;
#pragma unroll
  for (int s = 0; s < NSTEP; ++s) {
    const int k0 = 32 * s + 8 * khi;
    float4 fa = make_float4(0.f, 0.f, 0.f, 0.f);
    float4 fb = make_float4(0.f, 0.f, 0.f, 0.f);
    if (k0 < D_EMB)     fa = emb4[k0 >> 2];
    if (k0 + 4 < D_EMB) fb = emb4[(k0 >> 2) + 1];
    unsigned short h[8];
    h[0] = f32_bf16(fa.x); h[1] = f32_bf16(fa.y);
    h[2] = f32_bf16(fa.z); h[3] = f32_bf16(fa.w);
    h[4] = f32_bf16(fb.x); h[5] = f32_bf16(fb.y);
    h[6] = f32_bf16(fb.z); h[7] = f32_bf16(fb.w);
    short8 v;
#pragma unroll
    for (int j = 0; j < 8; ++j) {
      const float x = bf16_f32(h[j]);
      p += x * x;
      v[j] = (short)h[j];
    }
    *(short8*)(region + s * 512 + lane * 8) = v;
  }
  return p;
}

// Fused kernel: block = (batch b, 64-d chunk). 1024 blocks = 4/CU (grid-
// limited 50% occupancy). Wave w owns d-rows 16w..16w+15: B fragments in 40
// VGPRs (gather layout == MFMA operand layout); waves 0,1 also stage the two
// q-tiles to LDS during their gather. All HBM traffic is unique rows (L3
// absorbs cross-block re-reads -- measured FETCH ~= working set in R6).
__global__ __launch_bounds__(256, 4) void knrm_fused(
    const int* __restrict__ inputs_q, const int* __restrict__ inputs_d,
    const float* __restrict__ mask_d, const float* __restrict__ word_emb,
    float* __restrict__ partial)
{
  const int b    = blockIdx.y;
  const int j    = blockIdx.x;          // d-chunk 0..15
  const int tid  = threadIdx.x;
  const int wid  = tid >> 6;
  const int lane = tid & 63;
  const int khi  = lane >> 4;           // 0..3
  const int rl   = lane & 15;           // 0..15

  __shared__ __align__(16) short Alds[2 * FRAG_SHORTS];   // 20 KB (2 q-tiles)
  __shared__ float invq_lds[LQ];
  __shared__ float red[4][2][16][NBINS];                  // 5.5 KB

  const int dbase = b * LD + j * 64 + 16 * wid;           // this wave's 16 d rows

  // ---- waves 0,1: stage q-tile wid into LDS (canonical conversion)
  if (wid < 2) {
    const int tq = inputs_q[b * LQ + 16 * wid + rl];
    float pa = gather_convert_lds(word_emb + (size_t)tq * D_EMB,
                                  Alds + wid * FRAG_SHORTS, khi, lane);
    pa += __shfl_xor(pa, 16); pa += __shfl_xor(pa, 32);
    if (lane < 16) invq_lds[16 * wid + lane] = 1.f / fmaxf(sqrtf(pa), 1e-12f);
  }

  // ---- every wave: gather + convert its B subtile into registers
  const int td = inputs_d[dbase + rl];
  short8 bf[NSTEP];
  float pb = gather_convert(word_emb + (size_t)td * D_EMB, bf, khi);
  pb += __shfl_xor(pb, 16); pb += __shfl_xor(pb, 32);
  const float id = 1.f / fmaxf(sqrtf(pb), 1e-12f);   // own col's inv-norm
  __syncthreads();

  // ---- MFMA: acc[qt], A from LDS (b128), B from registers
  floatx4 acc[2] = {{0.f,0.f,0.f,0.f},{0.f,0.f,0.f,0.f}};
#pragma unroll
  for (int s = 0; s < NSTEP; ++s) {
    const short8 a0 = *(const short8*)(Alds + s * 512 + lane * 8);
    const short8 a1 = *(const short8*)(Alds + FRAG_SHORTS + s * 512 + lane * 8);
    acc[0] = __builtin_amdgcn_mfma_f32_16x16x32_bf16(a0, bf[s], acc[0], 0, 0, 0);
    acc[1] = __builtin_amdgcn_mfma_f32_16x16x32_bf16(a1, bf[s], acc[1], 0, 0, 0);
  }

  // ---- epilogue: normalize, RBF, pool over this wave's 16 d-cols
  // C/D layout: col = rl (d row), row = 4*khi + r (q within qt)
  const float md = mask_d[dbase + rl];
#pragma unroll
  for (int qt = 0; qt < 2; ++qt) {
    float ps[4][NBINS];
#pragma unroll
    for (int r = 0; r < 4; ++r) {
      const float iq = invq_lds[16 * qt + 4 * khi + r];
      const float sv = acc[qt][r] * iq * id;
#pragma unroll
      for (int k = 0; k < NBINS; ++k) {
        const float d = sv - c_mu[k];
        ps[r][k] = md * __expf(-d * d * c_is2[k]);
      }
    }
#pragma unroll
    for (int off = 1; off < 16; off <<= 1)
#pragma unroll
      for (int r = 0; r < 4; ++r)
#pragma unroll
        for (int k = 0; k < NBINS; ++k)
          ps[r][k] += __shfl_xor(ps[r][k], off);
    if (rl == 0)
#pragma unroll
      for (int r = 0; r < 4; ++r)
#pragma unroll
        for (int k = 0; k < NBINS; ++k)
          red[wid][qt][4 * khi + r][k] = ps[r][k];
  }
  __syncthreads();

  // combine 4 waves; partial layout [b][q][k][chunk] (finalize reads 16 floats)
  for (int v = tid; v < LQ * NBINS; v += 256) {
    const int q = v / NBINS, k = v % NBINS;
    const int qt = q >> 4, qr = q & 15;
    const float sv = red[0][qt][qr][k] + red[1][qt][qr][k]
                   + red[2][qt][qr][k] + red[3][qt][qr][k];
    partial[((size_t)(b * LQ + q) * NBINS + k) * NCHUNK + j] = sv;
  }
}

// Finalize: reduce chunks, log, IDF attention weight, sum over q, dense+tanh.
__global__ __launch_bounds__(128) void knrm_finalize(
    const float* __restrict__ partial, const int* __restrict__ inputs_q,
    const float* __restrict__ mask_q, const float* __restrict__ attn_table,
    const float* __restrict__ idf_w, const float* __restrict__ idf_b,
    const float* __restrict__ dense_w, const float* __restrict__ dense_b,
    float* __restrict__ out)
{
  const int b   = blockIdx.x;
  const int tid = threadIdx.x;
  __shared__ float pool[LQ][NBINS];
  __shared__ float wq_s[LQ];
  __shared__ float lps[NBINS];

  for (int v = tid; v < LQ * NBINS; v += 128) {
    const int q = v / NBINS, k = v % NBINS;
    const float* p = partial + ((size_t)(b * LQ + q) * NBINS + k) * NCHUNK;
    float s = 0.f;
#pragma unroll
    for (int t = 0; t < NCHUNK; ++t) s += p[t];
    pool[q][k] = logf(fmaxf(s, 1e-10f));
  }
  if (tid < LQ) {
    const int tok = inputs_q[b * LQ + tid];
    wq_s[tid] = mask_q[b * LQ + tid] * (attn_table[tok] * idf_w[0] + idf_b[0]);
  }
  __syncthreads();
  if (tid < NBINS) {
    float s = 0.f;
    for (int q = 0; q < LQ; ++q) s += pool[q][tid] * wq_s[q];
    lps[tid] = 0.01f * s;
  }
  __syncthreads();
  if (tid == 0) {
    float z = dense_b[0];
    for (int k = 0; k < NBINS; ++k) z += lps[k] * dense_w[k];
    out[b] = tanhf(z);
  }
}

extern "C" void kernel_launch(void* const* d_in, const int* in_sizes, int n_in,
                              void* d_out, int out_size, void* d_ws, size_t ws_size,
                              hipStream_t stream) {
  const int*   inputs_q  = (const int*)d_in[0];
  const int*   inputs_d  = (const int*)d_in[1];
  const float* mask_q    = (const float*)d_in[2];
  const float* mask_d    = (const float*)d_in[3];
  const float* word_emb  = (const float*)d_in[4];
  const float* attn_tab  = (const float*)d_in[5];
  const float* idf_w     = (const float*)d_in[6];
  const float* idf_b     = (const float*)d_in[7];
  const float* dense_w   = (const float*)d_in[8];
  const float* dense_b   = (const float*)d_in[9];
  float* out     = (float*)d_out;
  float* partial = (float*)d_ws;   // 64*32*11*16 f32 = 1.44 MB

  dim3 grid(NCHUNK, BATCH);        // 1024 blocks = 4 per CU
  knrm_fused<<<grid, 256, 0, stream>>>(inputs_q, inputs_d, mask_d, word_emb, partial);
  knrm_finalize<<<BATCH, 128, 0, stream>>>(partial, inputs_q, mask_q, attn_tab,
                                           idf_w, idf_b, dense_w, dense_b, out);
}